// Round 2
// baseline (195.478 us; speedup 1.0000x reference)
//
#include <hip/hip_runtime.h>

#define TOKS 65536
#define ED 64
#define NE 1024
#define CH_STRIDE 4096      // 64*64
#define B_STRIDE 262144     // 64*64*64

// ws byte layout:
//   enorm @ 0      : 1024 f32  (numpy-pairwise ||e||^2)   [4 KB]
//   idx   @ 4096   : 65536 i32                            [256 KB]
//   hist  @ 266240 : 1024 i32                             [4 KB]
//   loss  @ 270336 : 1 f64                                [8 B]

// numpy pairwise_sum for exactly 64 contiguous f32 values, unfused ops.
__device__ __forceinline__ float np_pairwise64(const float* a) {
    float r0 = a[0], r1 = a[1], r2 = a[2], r3 = a[3];
    float r4 = a[4], r5 = a[5], r6 = a[6], r7 = a[7];
    #pragma unroll
    for (int i = 8; i < 64; i += 8) {
        r0 = __fadd_rn(r0, a[i + 0]); r1 = __fadd_rn(r1, a[i + 1]);
        r2 = __fadd_rn(r2, a[i + 2]); r3 = __fadd_rn(r3, a[i + 3]);
        r4 = __fadd_rn(r4, a[i + 4]); r5 = __fadd_rn(r5, a[i + 5]);
        r6 = __fadd_rn(r6, a[i + 6]); r7 = __fadd_rn(r7, a[i + 7]);
    }
    return __fadd_rn(__fadd_rn(__fadd_rn(r0, r1), __fadd_rn(r2, r3)),
                     __fadd_rn(__fadd_rn(r4, r5), __fadd_rn(r6, r7)));
}

__global__ __launch_bounds__(256) void vq_prep(const float* __restrict__ emb,
                                               float* __restrict__ enorm,
                                               int* __restrict__ hist,
                                               double* __restrict__ lossAcc) {
    int j = blockIdx.x * 256 + threadIdx.x;
    if (j < NE) {
        float sq[ED];
        #pragma unroll
        for (int c = 0; c < ED; ++c) {
            float e = emb[j * ED + c];
            sq[c] = __fmul_rn(e, e);
        }
        enorm[j] = np_pairwise64(sq);
        hist[j] = 0;
    }
    if (blockIdx.x == 0 && threadIdx.x == 0) *lossAcc = 0.0;
}

// block = (64 tokens, 4 code-groups); each thread scans 256 codes for 1 token.
// Replicates np reference: d = f32(f32(znorm + enorm_j) - 2*mm_j),
// mm via sequential-k f32 FMA chain, argmin first-occurrence.
__global__ __launch_bounds__(256) void vq_argmin(const float* __restrict__ z,
                                                 const float* __restrict__ emb,
                                                 const float* __restrict__ enorm,
                                                 int* __restrict__ ws_idx,
                                                 float* __restrict__ out_idx) {
    const int tx = threadIdx.x;            // token lane 0..63
    const int ty = threadIdx.y;            // code group 0..3
    const int t = blockIdx.x * 64 + tx;
    const int b = t >> 12;
    const int hw = t & 4095;

    const float* zp = z + (size_t)b * B_STRIDE + hw;
    float zf[ED];
    #pragma unroll
    for (int c = 0; c < ED; ++c) zf[c] = zp[(size_t)c * CH_STRIDE];

    // znorm: replicate numpy pairwise sum of zf*zf bit-exactly (unfused)
    float sq[ED];
    #pragma unroll
    for (int c = 0; c < ED; ++c) sq[c] = __fmul_rn(zf[c], zf[c]);
    const float znorm = np_pairwise64(sq);

    // wave-uniform code-group base -> scalar loads for codeword rows
    const int jbase = __builtin_amdgcn_readfirstlane(ty << 8);

    float best = 3.4e38f;
    int bj = jbase;
    for (int j = 0; j < 256; j += 2) {
        const float* __restrict__ e0 = emb + (size_t)(jbase + j) * ED;
        const float* __restrict__ e1 = e0 + ED;
        float c0 = 0.f, c1 = 0.f;          // sequential-k FMA chains (BLAS-like)
        #pragma unroll
        for (int k = 0; k < ED; ++k) {
            c0 = __fmaf_rn(zf[k], e0[k], c0);
            c1 = __fmaf_rn(zf[k], e1[k], c1);
        }
        float d0 = __fsub_rn(__fadd_rn(znorm, enorm[jbase + j]),     2.0f * c0);
        float d1 = __fsub_rn(__fadd_rn(znorm, enorm[jbase + j + 1]), 2.0f * c1);
        if (d0 < best) { best = d0; bj = jbase + j; }      // strict <: first-min
        if (d1 < best) { best = d1; bj = jbase + j + 1; }
    }

    __shared__ float s_best[4][64];
    __shared__ int s_bj[4][64];
    s_best[ty][tx] = best;
    s_bj[ty][tx] = bj;
    __syncthreads();
    if (ty == 0) {
        float bb = s_best[0][tx];
        int jj = s_bj[0][tx];
        #pragma unroll
        for (int g = 1; g < 4; ++g) {                 // ascending groups: tie -> lowest j
            float v = s_best[g][tx];
            if (v < bb) { bb = v; jj = s_bj[g][tx]; }
        }
        ws_idx[t] = jj;
        out_idx[t] = (float)jj;
    }
}

__global__ __launch_bounds__(256) void vq_gather(const float* __restrict__ z,
                                                 const float* __restrict__ emb,
                                                 const int* __restrict__ ws_idx,
                                                 float* __restrict__ zq,
                                                 int* __restrict__ hist,
                                                 double* __restrict__ lossAcc) {
    const int t = blockIdx.x * 256 + threadIdx.x;
    const int b = t >> 12;
    const int hw = t & 4095;
    const int idx = ws_idx[t];
    atomicAdd(&hist[idx], 1);
    const float* e = emb + (size_t)idx * ED;
    const float* zp = z + (size_t)b * B_STRIDE + hw;
    float* o = zq + (size_t)b * B_STRIDE + hw;
    double ls = 0.0;
    #pragma unroll
    for (int c = 0; c < ED; ++c) {
        float ev = e[c];
        float zv = zp[(size_t)c * CH_STRIDE];
        o[(size_t)c * CH_STRIDE] = ev;                 // STE: z_q == emb[idx] numerically
        float d = ev - zv;
        ls += (double)(d * d);
    }
    #pragma unroll
    for (int off = 32; off > 0; off >>= 1) ls += __shfl_down(ls, off, 64);
    __shared__ double wsum[4];
    if ((threadIdx.x & 63) == 0) wsum[threadIdx.x >> 6] = ls;
    __syncthreads();
    if (threadIdx.x == 0) {
        double tot = wsum[0] + wsum[1] + wsum[2] + wsum[3];
        atomicAdd(lossAcc, tot);
    }
}

__global__ __launch_bounds__(256) void vq_final(const int* __restrict__ hist,
                                                const double* __restrict__ lossAcc,
                                                float* __restrict__ outs) {
    __shared__ double red[256];
    double acc = 0.0;
    for (int j = threadIdx.x; j < NE; j += 256) {
        double em = (double)hist[j] * (1.0 / 65536.0);
        acc += em * log(em + 1e-10);
    }
    red[threadIdx.x] = acc;
    __syncthreads();
    for (int s = 128; s > 0; s >>= 1) {
        if (threadIdx.x < s) red[threadIdx.x] += red[threadIdx.x + s];
        __syncthreads();
    }
    if (threadIdx.x == 0) {
        outs[0] = (float)(1.25 * (*lossAcc) * (1.0 / 4194304.0));  // (1+beta)*MSE
        outs[1] = (float)exp(-red[0]);                              // perplexity
    }
}

extern "C" void kernel_launch(void* const* d_in, const int* in_sizes, int n_in,
                              void* d_out, int out_size, void* d_ws, size_t ws_size,
                              hipStream_t stream) {
    const float* z = (const float*)d_in[0];
    const float* emb = (const float*)d_in[1];
    float* out = (float*)d_out;

    char* ws = (char*)d_ws;
    float* enorm = (float*)ws;
    int* ws_idx = (int*)(ws + 4096);
    int* hist = (int*)(ws + 266240);
    double* lossAcc = (double*)(ws + 270336);

    float* zq = out;                       // [0, 4194304)
    float* scalars = out + 4194304;        // loss, perplexity
    float* out_idx = out + 4194306;        // 65536 indices as float

    vq_prep<<<4, 256, 0, stream>>>(emb, enorm, hist, lossAcc);
    dim3 bB(64, 4);
    vq_argmin<<<1024, bB, 0, stream>>>(z, emb, enorm, ws_idx, out_idx);
    vq_gather<<<256, 256, 0, stream>>>(z, emb, ws_idx, zq, hist, lossAcc);
    vq_final<<<1, 256, 0, stream>>>(hist, lossAcc, scalars);
}

// Round 3
// 182.258 us; speedup vs baseline: 1.0725x; 1.0725x over previous
//
#include <hip/hip_runtime.h>

#define TOKS 65536
#define ED 64
#define NE 1024
#define CH_STRIDE 4096      // 64*64
#define B_STRIDE 262144     // 64*64*64

typedef float v2f __attribute__((ext_vector_type(2)));

// ws byte layout:
//   epair @ 0      : 512 pairs x 64 k x float2       [256 KB]  {emb[2p][k], emb[2p+1][k]}
//   enorm @ 262144 : 1024 f32 (numpy-pairwise ||e||^2) [4 KB]
//   idx   @ 266240 : 65536 i32                        [256 KB]
//   hist  @ 528384 : 1024 i32                         [4 KB]
//   loss  @ 532480 : 1 f64                            [8 B]

// numpy pairwise_sum for exactly 64 contiguous f32 values, unfused ops.
__device__ __forceinline__ float np_pairwise64(const float* a) {
    float r0 = a[0], r1 = a[1], r2 = a[2], r3 = a[3];
    float r4 = a[4], r5 = a[5], r6 = a[6], r7 = a[7];
    #pragma unroll
    for (int i = 8; i < 64; i += 8) {
        r0 = __fadd_rn(r0, a[i + 0]); r1 = __fadd_rn(r1, a[i + 1]);
        r2 = __fadd_rn(r2, a[i + 2]); r3 = __fadd_rn(r3, a[i + 3]);
        r4 = __fadd_rn(r4, a[i + 4]); r5 = __fadd_rn(r5, a[i + 5]);
        r6 = __fadd_rn(r6, a[i + 6]); r7 = __fadd_rn(r7, a[i + 7]);
    }
    return __fadd_rn(__fadd_rn(__fadd_rn(r0, r1), __fadd_rn(r2, r3)),
                     __fadd_rn(__fadd_rn(r4, r5), __fadd_rn(r6, r7)));
}

__global__ __launch_bounds__(256) void vq_prep(const float* __restrict__ emb,
                                               float* __restrict__ epair,
                                               float* __restrict__ enorm,
                                               int* __restrict__ hist,
                                               double* __restrict__ lossAcc) {
    int j = blockIdx.x * 256 + threadIdx.x;
    if (j < NE) {
        const int p = j >> 1;          // pair index
        const int half = j & 1;
        float sq[ED];
        #pragma unroll
        for (int c = 0; c < ED; ++c) {
            float e = emb[j * ED + c];
            sq[c] = __fmul_rn(e, e);
            // epair[p][c] = {emb[2p][c], emb[2p+1][c]} as interleaved floats
            epair[((size_t)p * ED + c) * 2 + half] = e;
        }
        enorm[j] = np_pairwise64(sq);
        hist[j] = 0;
    }
    if (blockIdx.x == 0 && threadIdx.x == 0) *lossAcc = 0.0;
}

// block = (64 tokens, 4 code-groups); each thread scans 128 code PAIRS for 1 token.
// Packed v_pk_fma_f32: acc2 = {chain(2p), chain(2p+1)}; each half is the exact
// sequential-k __fmaf_rn chain the np/OpenBLAS reference uses (bit-identical to R2).
__global__ __launch_bounds__(256) void vq_argmin(const float* __restrict__ z,
                                                 const v2f* __restrict__ epair,
                                                 const v2f* __restrict__ enormp,
                                                 int* __restrict__ ws_idx,
                                                 float* __restrict__ out_idx) {
    const int tx = threadIdx.x;            // token lane 0..63
    const int ty = threadIdx.y;            // code group 0..3
    const int t = blockIdx.x * 64 + tx;
    const int b = t >> 12;
    const int hw = t & 4095;

    const float* zp = z + (size_t)b * B_STRIDE + hw;
    v2f zz[ED];                            // duplicated token vector (128 VGPR)
    #pragma unroll
    for (int c = 0; c < ED; ++c) {
        float v = zp[(size_t)c * CH_STRIDE];
        zz[c].x = v; zz[c].y = v;
    }

    // znorm: numpy pairwise sum of zf*zf, bit-exact, streamed (no sq[] array)
    float rr[8];
    #pragma unroll
    for (int m = 0; m < 8; ++m) rr[m] = __fmul_rn(zz[m].x, zz[m].x);
    #pragma unroll
    for (int i = 8; i < 64; i += 8) {
        #pragma unroll
        for (int m = 0; m < 8; ++m)
            rr[m] = __fadd_rn(rr[m], __fmul_rn(zz[i + m].x, zz[i + m].x));
    }
    const float znorm =
        __fadd_rn(__fadd_rn(__fadd_rn(rr[0], rr[1]), __fadd_rn(rr[2], rr[3])),
                  __fadd_rn(__fadd_rn(rr[4], rr[5]), __fadd_rn(rr[6], rr[7])));

    // wave-uniform code-pair base -> scalar loads for epair rows
    const int pbase = __builtin_amdgcn_readfirstlane(ty << 7);   // 128 pairs/group

    float best = 3.4e38f;
    int bj = pbase << 1;
    for (int p = 0; p < 128; ++p) {
        const v2f* __restrict__ ep = epair + (size_t)(pbase + p) * ED;
        v2f acc; acc.x = 0.f; acc.y = 0.f;
        #pragma unroll
        for (int k = 0; k < ED; ++k)
            acc = __builtin_elementwise_fma(zz[k], ep[k], acc);   // v_pk_fma_f32
        v2f en = enormp[pbase + p];
        float d0 = __fsub_rn(__fadd_rn(znorm, en.x), 2.0f * acc.x);
        float d1 = __fsub_rn(__fadd_rn(znorm, en.y), 2.0f * acc.y);
        const int j0 = (pbase + p) << 1;
        if (d0 < best) { best = d0; bj = j0; }      // strict <: first-min wins
        if (d1 < best) { best = d1; bj = j0 + 1; }
    }

    __shared__ float s_best[4][64];
    __shared__ int s_bj[4][64];
    s_best[ty][tx] = best;
    s_bj[ty][tx] = bj;
    __syncthreads();
    if (ty == 0) {
        float bb = s_best[0][tx];
        int jj = s_bj[0][tx];
        #pragma unroll
        for (int g = 1; g < 4; ++g) {                 // ascending groups: tie -> lowest j
            float v = s_best[g][tx];
            if (v < bb) { bb = v; jj = s_bj[g][tx]; }
        }
        ws_idx[t] = jj;
        out_idx[t] = (float)jj;
    }
}

__global__ __launch_bounds__(256) void vq_gather(const float* __restrict__ z,
                                                 const float* __restrict__ emb,
                                                 const int* __restrict__ ws_idx,
                                                 float* __restrict__ zq,
                                                 int* __restrict__ hist,
                                                 double* __restrict__ lossAcc) {
    const int t = blockIdx.x * 256 + threadIdx.x;
    const int b = t >> 12;
    const int hw = t & 4095;
    const int idx = ws_idx[t];
    atomicAdd(&hist[idx], 1);
    const float* e = emb + (size_t)idx * ED;
    const float* zp = z + (size_t)b * B_STRIDE + hw;
    float* o = zq + (size_t)b * B_STRIDE + hw;
    double ls = 0.0;
    #pragma unroll
    for (int c = 0; c < ED; ++c) {
        float ev = e[c];
        float zv = zp[(size_t)c * CH_STRIDE];
        o[(size_t)c * CH_STRIDE] = ev;                 // STE: z_q == emb[idx] numerically
        float d = ev - zv;
        ls += (double)(d * d);
    }
    #pragma unroll
    for (int off = 32; off > 0; off >>= 1) ls += __shfl_down(ls, off, 64);
    __shared__ double wsum[4];
    if ((threadIdx.x & 63) == 0) wsum[threadIdx.x >> 6] = ls;
    __syncthreads();
    if (threadIdx.x == 0) {
        double tot = wsum[0] + wsum[1] + wsum[2] + wsum[3];
        atomicAdd(lossAcc, tot);
    }
}

__global__ __launch_bounds__(256) void vq_final(const int* __restrict__ hist,
                                                const double* __restrict__ lossAcc,
                                                float* __restrict__ outs) {
    __shared__ double red[256];
    double acc = 0.0;
    for (int j = threadIdx.x; j < NE; j += 256) {
        double em = (double)hist[j] * (1.0 / 65536.0);
        acc += em * log(em + 1e-10);
    }
    red[threadIdx.x] = acc;
    __syncthreads();
    for (int s = 128; s > 0; s >>= 1) {
        if (threadIdx.x < s) red[threadIdx.x] += red[threadIdx.x + s];
        __syncthreads();
    }
    if (threadIdx.x == 0) {
        outs[0] = (float)(1.25 * (*lossAcc) * (1.0 / 4194304.0));  // (1+beta)*MSE
        outs[1] = (float)exp(-red[0]);                              // perplexity
    }
}

extern "C" void kernel_launch(void* const* d_in, const int* in_sizes, int n_in,
                              void* d_out, int out_size, void* d_ws, size_t ws_size,
                              hipStream_t stream) {
    const float* z = (const float*)d_in[0];
    const float* emb = (const float*)d_in[1];
    float* out = (float*)d_out;

    char* ws = (char*)d_ws;
    float* epair = (float*)ws;
    float* enorm = (float*)(ws + 262144);
    int* ws_idx = (int*)(ws + 266240);
    int* hist = (int*)(ws + 528384);
    double* lossAcc = (double*)(ws + 532480);

    float* zq = out;                       // [0, 4194304)
    float* scalars = out + 4194304;        // loss, perplexity
    float* out_idx = out + 4194306;        // 65536 indices as float

    vq_prep<<<4, 256, 0, stream>>>(emb, epair, enorm, hist, lossAcc);
    dim3 bB(64, 4);
    vq_argmin<<<1024, bB, 0, stream>>>(z, (const v2f*)epair, (const v2f*)enorm,
                                       ws_idx, out_idx);
    vq_gather<<<256, 256, 0, stream>>>(z, emb, ws_idx, zq, hist, lossAcc);
    vq_final<<<1, 256, 0, stream>>>(hist, lossAcc, scalars);
}

// Round 4
// 96.839 us; speedup vs baseline: 2.0186x; 1.8821x over previous
//
#include <hip/hip_runtime.h>

#define TOKS 65536
#define ED 64
#define NE 1024
#define CH_STRIDE 4096      // 64*64
#define B_STRIDE 262144     // 64*64*64

typedef __bf16 bf16x8 __attribute__((ext_vector_type(8)));
typedef float f32x16 __attribute__((ext_vector_type(16)));
typedef float f32x4 __attribute__((ext_vector_type(4)));
typedef unsigned short ushort_t;
typedef unsigned int uint_t;

// ws layout:
//   efrag @ 0      : 32ct x 4ks x 2hl x 64lane x 8 bf16   [256 KB]  frags of (-2*emb)
//   enorm @ 262144 : 1024 f32 (np-pairwise ||e||^2, exact) [4 KB]
//   idx   @ 266240 : 65536 i32                             [256 KB]
//   hist  @ 528384 : 1024 i32                              [4 KB]
//   loss  @ 532480 : 1 f64                                 [8 B]
// d_out zq region [0,4194304) floats doubles as Z-fragment storage (prep_z
// writes, argmin reads, gather overwrites). out[4194306..] holds znorm
// until argmin overwrites it with the final indices.

__device__ __forceinline__ ushort_t f2bf(float x) {
    uint_t u = __float_as_uint(x);
    uint_t r = u + 0x7FFFu + ((u >> 16) & 1u);   // RNE
    return (ushort_t)(r >> 16);
}
__device__ __forceinline__ float bf2f(ushort_t h) {
    return __uint_as_float(((uint_t)h) << 16);
}

// numpy pairwise_sum for exactly 64 f32 values, unfused ops (bit-exact).
__device__ __forceinline__ float np_pairwise64(const float* a) {
    float r0 = a[0], r1 = a[1], r2 = a[2], r3 = a[3];
    float r4 = a[4], r5 = a[5], r6 = a[6], r7 = a[7];
    #pragma unroll
    for (int i = 8; i < 64; i += 8) {
        r0 = __fadd_rn(r0, a[i + 0]); r1 = __fadd_rn(r1, a[i + 1]);
        r2 = __fadd_rn(r2, a[i + 2]); r3 = __fadd_rn(r3, a[i + 3]);
        r4 = __fadd_rn(r4, a[i + 4]); r5 = __fadd_rn(r5, a[i + 5]);
        r6 = __fadd_rn(r6, a[i + 6]); r7 = __fadd_rn(r7, a[i + 7]);
    }
    return __fadd_rn(__fadd_rn(__fadd_rn(r0, r1), __fadd_rn(r2, r3)),
                     __fadd_rn(__fadd_rn(r4, r5), __fadd_rn(r6, r7)));
}

// ---- prep E: enorm (exact), A-fragments of -2*emb (bf16 hi/lo), hist/loss init
__global__ __launch_bounds__(256) void vq_prep_e(const float* __restrict__ emb,
                                                 ushort_t* __restrict__ efrag,
                                                 float* __restrict__ enorm,
                                                 int* __restrict__ hist,
                                                 double* __restrict__ lossAcc) {
    int j = blockIdx.x * 256 + threadIdx.x;
    if (j < NE) {
        const int ct = j >> 5, m = j & 31;
        float sq[ED];
        #pragma unroll
        for (int k = 0; k < ED; ++k) {
            float e = emb[j * ED + k];
            sq[k] = __fmul_rn(e, e);
            float v = -2.0f * e;                    // exact (x2)
            ushort_t h = f2bf(v);
            float resid = v - bf2f(h);              // exact (close values)
            ushort_t l = f2bf(resid);
            const int ks = k >> 4, khalf = (k >> 3) & 1, i = k & 7;
            const int lane = m + 32 * khalf;
            efrag[(size_t)(((ct * 4 + ks) * 2 + 0) * 512) + lane * 8 + i] = h;
            efrag[(size_t)(((ct * 4 + ks) * 2 + 1) * 512) + lane * 8 + i] = l;
        }
        enorm[j] = np_pairwise64(sq);
        hist[j] = 0;
    }
    if (blockIdx.x == 0 && threadIdx.x == 0) *lossAcc = 0.0;
}

// ---- prep Z: znorm (exact, into out-idx alias), B-fragments of z (bf16 hi/lo)
__global__ __launch_bounds__(256) void vq_prep_z(const float* __restrict__ z,
                                                 ushort_t* __restrict__ zfrag,
                                                 float* __restrict__ znalias) {
    const int t = blockIdx.x * 256 + threadIdx.x;
    const int tt = t >> 5, n = t & 31;
    const float* zp = z + (size_t)(t >> 12) * B_STRIDE + (t & 4095);
    float zv[ED];
    #pragma unroll
    for (int k = 0; k < ED; ++k) zv[k] = zp[(size_t)k * CH_STRIDE];

    float sq[ED];
    #pragma unroll
    for (int k = 0; k < ED; ++k) sq[k] = __fmul_rn(zv[k], zv[k]);
    znalias[t] = np_pairwise64(sq);

    #pragma unroll
    for (int k = 0; k < ED; ++k) {
        ushort_t h = f2bf(zv[k]);
        float resid = zv[k] - bf2f(h);
        ushort_t l = f2bf(resid);
        const int ks = k >> 4, khalf = (k >> 3) & 1, i = k & 7;
        const int lane = n + 32 * khalf;
        zfrag[(size_t)(((tt * 4 + ks) * 2 + 0) * 512) + lane * 8 + i] = h;
        zfrag[(size_t)(((tt * 4 + ks) * 2 + 1) * 512) + lane * 8 + i] = l;
    }
}

// ---- MFMA filter + exact rescore. Block = 4 waves, wave = 1 token-tile (32 tok).
// acc(code row, token col) = enorm_j - 2*z.e (3-term bf16 split); top-3 per lane,
// union with partner lane, exact f32 rescore picks np argmin.
__global__ __launch_bounds__(256) void vq_argmin_mfma(
    const ushort_t* __restrict__ zfrag,
    const ushort_t* __restrict__ efrag,
    const float* __restrict__ enorm,
    const float* __restrict__ znalias,
    const float* __restrict__ z,
    const float* __restrict__ emb,
    int* __restrict__ ws_idx,
    float* __restrict__ out_idx) {
    const int tid = threadIdx.x;
    const int w = tid >> 6, lane = tid & 63;
    const int tt = blockIdx.x * 4 + w;
    const int n = lane & 31, hi = lane >> 5;
    const int t = tt * 32 + n;

    __shared__ uint4 sm[2][512];          // double-buffered 8 KB E-tiles

    // resident Z B-frags (hi/lo x 4 k-steps)
    bf16x8 zb0[4], zb1[4];
    {
        const bf16x8* zp = (const bf16x8*)(zfrag + (size_t)tt * 4096);
        #pragma unroll
        for (int ks = 0; ks < 4; ++ks) {
            zb0[ks] = zp[(ks * 2 + 0) * 64 + lane];
            zb1[ks] = zp[(ks * 2 + 1) * 64 + lane];
        }
    }

    float t0 = 3.4e38f, t1 = 3.4e38f, t2 = 3.4e38f;
    int j0 = 0, j1 = 0, j2 = 0;

    const uint4* eg = (const uint4*)efrag;
    // prologue: stage ct=0
    {
        uint4 s0 = eg[tid * 2], s1 = eg[tid * 2 + 1];
        ((uint4*)sm[0])[tid * 2] = s0;
        ((uint4*)sm[0])[tid * 2 + 1] = s1;
    }
    __syncthreads();

    for (int ct = 0; ct < 32; ++ct) {
        uint4 r0, r1;
        if (ct < 31) {                     // issue next-tile loads early
            r0 = eg[(size_t)(ct + 1) * 512 + tid * 2];
            r1 = eg[(size_t)(ct + 1) * 512 + tid * 2 + 1];
        }
        // acc init = enorm rows (folds +||e||^2 into the MFMA chain)
        f32x16 acc;
        #pragma unroll
        for (int q = 0; q < 4; ++q) {
            f32x4 e4 = *(const f32x4*)(enorm + ct * 32 + q * 8 + hi * 4);
            acc[q * 4 + 0] = e4.x; acc[q * 4 + 1] = e4.y;
            acc[q * 4 + 2] = e4.z; acc[q * 4 + 3] = e4.w;
        }
        const bf16x8* ep = (const bf16x8*)sm[ct & 1];
        #pragma unroll
        for (int ks = 0; ks < 4; ++ks) {
            bf16x8 ah = ep[(ks * 2 + 0) * 64 + lane];
            bf16x8 al = ep[(ks * 2 + 1) * 64 + lane];
            acc = __builtin_amdgcn_mfma_f32_32x32x16_bf16(ah, zb0[ks], acc, 0, 0, 0);
            acc = __builtin_amdgcn_mfma_f32_32x32x16_bf16(ah, zb1[ks], acc, 0, 0, 0);
            acc = __builtin_amdgcn_mfma_f32_32x32x16_bf16(al, zb0[ks], acc, 0, 0, 0);
        }
        // top-3 insertion over the 16 code-rows this lane owns
        #pragma unroll
        for (int r = 0; r < 16; ++r) {
            float v = acc[r];
            int j = ct * 32 + (r & 3) + 8 * (r >> 2) + 4 * hi;
            bool b0 = v < t0, b1 = v < t1, b2 = v < t2;
            t2 = b1 ? t1 : (b2 ? v : t2);  j2 = b1 ? j1 : (b2 ? j : j2);
            t1 = b0 ? t0 : (b1 ? v : t1);  j1 = b0 ? j0 : (b1 ? j : j1);
            t0 = b0 ? v : t0;              j0 = b0 ? j : j0;
        }
        __syncthreads();                   // everyone done reading sm[ct&1]
        if (ct < 31) {
            ((uint4*)sm[(ct + 1) & 1])[tid * 2] = r0;
            ((uint4*)sm[(ct + 1) & 1])[tid * 2 + 1] = r1;
        }
        __syncthreads();                   // next tile visible
    }

    // candidate union with partner lane (other 16-row half of this token col)
    int p0 = __shfl_xor(j0, 32, 64);
    int p1 = __shfl_xor(j1, 32, 64);
    int p2 = __shfl_xor(j2, 32, 64);

    if (hi == 0) {
        const float* zp = z + (size_t)(t >> 12) * B_STRIDE + (t & 4095);
        float zr[64];
        #pragma unroll
        for (int k = 0; k < 64; ++k) zr[k] = zp[(size_t)k * CH_STRIDE];
        const float zn = znalias[t];
        int cand[6] = {j0, j1, j2, p0, p1, p2};
        float bd = 3.4e38f; int bj = 1 << 30;
        #pragma unroll
        for (int c = 0; c < 6; ++c) {
            const int j = cand[c];
            const float* e = emb + (size_t)j * 64;
            float a0 = 0.f;
            #pragma unroll
            for (int k = 0; k < 64; ++k) a0 = __fmaf_rn(zr[k], e[k], a0);
            float d = __fsub_rn(__fadd_rn(zn, enorm[j]), 2.0f * a0);
            if (d < bd || (d == bd && j < bj)) { bd = d; bj = j; }
        }
        ws_idx[t] = bj;
        out_idx[t] = (float)bj;            // overwrites znorm alias (last use above)
    }
}

__global__ __launch_bounds__(256) void vq_gather(const float* __restrict__ z,
                                                 const float* __restrict__ emb,
                                                 const int* __restrict__ ws_idx,
                                                 float* __restrict__ zq,
                                                 int* __restrict__ hist,
                                                 double* __restrict__ lossAcc) {
    const int t = blockIdx.x * 256 + threadIdx.x;
    const int b = t >> 12;
    const int hw = t & 4095;
    const int idx = ws_idx[t];
    atomicAdd(&hist[idx], 1);
    const float* e = emb + (size_t)idx * ED;
    const float* zp = z + (size_t)b * B_STRIDE + hw;
    float* o = zq + (size_t)b * B_STRIDE + hw;
    double ls = 0.0;
    #pragma unroll
    for (int c = 0; c < ED; ++c) {
        float ev = e[c];
        float zv = zp[(size_t)c * CH_STRIDE];
        o[(size_t)c * CH_STRIDE] = ev;
        float d = ev - zv;
        ls += (double)(d * d);
    }
    #pragma unroll
    for (int off = 32; off > 0; off >>= 1) ls += __shfl_down(ls, off, 64);
    __shared__ double wsum[4];
    if ((threadIdx.x & 63) == 0) wsum[threadIdx.x >> 6] = ls;
    __syncthreads();
    if (threadIdx.x == 0) {
        double tot = wsum[0] + wsum[1] + wsum[2] + wsum[3];
        atomicAdd(lossAcc, tot);
    }
}

__global__ __launch_bounds__(256) void vq_final(const int* __restrict__ hist,
                                                const double* __restrict__ lossAcc,
                                                float* __restrict__ outs) {
    __shared__ double red[256];
    double acc = 0.0;
    for (int j = threadIdx.x; j < NE; j += 256) {
        double em = (double)hist[j] * (1.0 / 65536.0);
        acc += em * log(em + 1e-10);
    }
    red[threadIdx.x] = acc;
    __syncthreads();
    for (int s = 128; s > 0; s >>= 1) {
        if (threadIdx.x < s) red[threadIdx.x] += red[threadIdx.x + s];
        __syncthreads();
    }
    if (threadIdx.x == 0) {
        outs[0] = (float)(1.25 * (*lossAcc) * (1.0 / 4194304.0));
        outs[1] = (float)exp(-red[0]);
    }
}

extern "C" void kernel_launch(void* const* d_in, const int* in_sizes, int n_in,
                              void* d_out, int out_size, void* d_ws, size_t ws_size,
                              hipStream_t stream) {
    const float* z = (const float*)d_in[0];
    const float* emb = (const float*)d_in[1];
    float* out = (float*)d_out;

    char* ws = (char*)d_ws;
    ushort_t* efrag = (ushort_t*)ws;
    float* enorm = (float*)(ws + 262144);
    int* ws_idx = (int*)(ws + 266240);
    int* hist = (int*)(ws + 528384);
    double* lossAcc = (double*)(ws + 532480);

    float* zq = out;                        // final z_q (and temp Z-fragment store)
    ushort_t* zfrag = (ushort_t*)out;       // 16 MB, exactly the zq region
    float* scalars = out + 4194304;         // loss, perplexity
    float* out_idx = out + 4194306;         // znorm temp, then final indices

    vq_prep_e<<<4, 256, 0, stream>>>(emb, efrag, enorm, hist, lossAcc);
    vq_prep_z<<<256, 256, 0, stream>>>(z, zfrag, out_idx);
    vq_argmin_mfma<<<512, 256, 0, stream>>>(zfrag, efrag, enorm, out_idx, z, emb,
                                            ws_idx, out_idx);
    vq_gather<<<256, 256, 0, stream>>>(z, emb, ws_idx, zq, hist, lossAcc);
    vq_final<<<1, 256, 0, stream>>>(hist, lossAcc, scalars);
}

// Round 5
// 83.932 us; speedup vs baseline: 2.3290x; 1.1538x over previous
//
#include <hip/hip_runtime.h>

#define TOKS 65536
#define ED 64
#define NE 1024
#define CH_STRIDE 4096      // 64*64
#define B_STRIDE 262144     // 64*64*64

typedef __bf16 bf16x8 __attribute__((ext_vector_type(8)));
typedef float f32x16 __attribute__((ext_vector_type(16)));
typedef float f32x4 __attribute__((ext_vector_type(4)));
typedef unsigned short ushort_t;
typedef unsigned int uint_t;

// ws layout:
//   efrag @ 0      : 32ct x 4ks x 2hl x 64lane x 8 bf16    [256 KB]  frags of (-2*emb)
//   enorm @ 262144 : 1024 f32 (np-pairwise ||e||^2, exact)  [4 KB]
//   idx   @ 266240 : 65536 i32                              [256 KB]
//   hist  @ 528384 : 1024 i32                               [4 KB]
//   loss  @ 532480 : 1 f64                                  [8 B]

__device__ __forceinline__ ushort_t f2bf(float x) {
    uint_t u = __float_as_uint(x);
    uint_t r = u + 0x7FFFu + ((u >> 16) & 1u);   // RNE
    return (ushort_t)(r >> 16);
}
__device__ __forceinline__ float bf2f(ushort_t h) {
    return __uint_as_float(((uint_t)h) << 16);
}

// numpy pairwise_sum for exactly 64 f32 values, unfused ops (bit-exact).
__device__ __forceinline__ float np_pairwise64(const float* a) {
    float r0 = a[0], r1 = a[1], r2 = a[2], r3 = a[3];
    float r4 = a[4], r5 = a[5], r6 = a[6], r7 = a[7];
    #pragma unroll
    for (int i = 8; i < 64; i += 8) {
        r0 = __fadd_rn(r0, a[i + 0]); r1 = __fadd_rn(r1, a[i + 1]);
        r2 = __fadd_rn(r2, a[i + 2]); r3 = __fadd_rn(r3, a[i + 3]);
        r4 = __fadd_rn(r4, a[i + 4]); r5 = __fadd_rn(r5, a[i + 5]);
        r6 = __fadd_rn(r6, a[i + 6]); r7 = __fadd_rn(r7, a[i + 7]);
    }
    return __fadd_rn(__fadd_rn(__fadd_rn(r0, r1), __fadd_rn(r2, r3)),
                     __fadd_rn(__fadd_rn(r4, r5), __fadd_rn(r6, r7)));
}

// ---- prep E: enorm (exact), A-fragments of -2*emb (bf16 hi/lo), hist/loss init
__global__ __launch_bounds__(256) void vq_prep_e(const float* __restrict__ emb,
                                                 ushort_t* __restrict__ efrag,
                                                 float* __restrict__ enorm,
                                                 int* __restrict__ hist,
                                                 double* __restrict__ lossAcc) {
    int j = blockIdx.x * 256 + threadIdx.x;
    if (j < NE) {
        const int ct = j >> 5, m = j & 31;
        float sq[ED];
        #pragma unroll
        for (int k = 0; k < ED; ++k) {
            float e = emb[j * ED + k];
            sq[k] = __fmul_rn(e, e);
            float v = -2.0f * e;                    // exact (x2)
            ushort_t h = f2bf(v);
            float resid = v - bf2f(h);              // exact
            ushort_t l = f2bf(resid);
            const int ks = k >> 4, khalf = (k >> 3) & 1, i = k & 7;
            const int lane = m + 32 * khalf;
            efrag[(size_t)(((ct * 4 + ks) * 2 + 0) * 512) + lane * 8 + i] = h;
            efrag[(size_t)(((ct * 4 + ks) * 2 + 1) * 512) + lane * 8 + i] = l;
        }
        enorm[j] = np_pairwise64(sq);
        hist[j] = 0;
    }
    if (blockIdx.x == 0 && threadIdx.x == 0) *lossAcc = 0.0;
}

// ---- MFMA filter (barrier-free, LDS-free scan) + exact rescore.
// Block = 4 waves = 2 token-tiles x 2 ct-halves. Each wave: 32 tokens x 512 codes.
// Per-lane top-2 (lane-set = 256 codes), 8 candidates/token, exact f32 rescore.
__global__ __launch_bounds__(256) void vq_argmin_mfma(
    const float* __restrict__ z,
    const ushort_t* __restrict__ efrag,
    const float* __restrict__ enorm,
    const float* __restrict__ emb,
    int* __restrict__ ws_idx,
    float* __restrict__ out_idx) {
    const int tid = threadIdx.x;
    const int w = tid >> 6, lane = tid & 63;
    const int tile = blockIdx.x * 2 + (w >> 1);  // waves 0,1 -> tile A; 2,3 -> B
    const int h = w & 1;                         // ct half (codes 512h..512h+511)
    const int n = lane & 31, kh = lane >> 5;
    const int hi = kh;
    const int t = tile * 32 + n;

    // ---- build Z B-frags in-register (layout = R4's verified prep_z mapping)
    const float* zbase = z + (size_t)(t >> 12) * B_STRIDE + (t & 4095);
    bf16x8 zb0[4], zb1[4];
    #pragma unroll
    for (int ks = 0; ks < 4; ++ks) {
        #pragma unroll
        for (int i = 0; i < 8; ++i) {
            float v = zbase[(size_t)(ks * 16 + kh * 8 + i) * CH_STRIDE];
            ushort_t hb = f2bf(v);
            float resid = v - bf2f(hb);
            ushort_t lb = f2bf(resid);
            union { ushort_t u; __bf16 b; } c1, c2;
            c1.u = hb; c2.u = lb;
            zb0[ks][i] = c1.b;
            zb1[ks][i] = c2.b;
        }
    }

    // ---- scan 16 E-tiles: d~ = enorm_j - 2 z.e (3-term bf16 split), top-2/lane
    float t0 = 3.4e38f, t1 = 3.4e38f;
    int j0 = 0, j1 = 0;
    const bf16x8* eg = (const bf16x8*)efrag;
    for (int ct = 0; ct < 16; ++ct) {
        const int gct = h * 16 + ct;
        f32x16 acc;
        #pragma unroll
        for (int q = 0; q < 4; ++q) {
            f32x4 e4 = *(const f32x4*)(enorm + gct * 32 + q * 8 + hi * 4);
            acc[q * 4 + 0] = e4.x; acc[q * 4 + 1] = e4.y;
            acc[q * 4 + 2] = e4.z; acc[q * 4 + 3] = e4.w;
        }
        #pragma unroll
        for (int ks = 0; ks < 4; ++ks) {
            bf16x8 ah = eg[(size_t)((gct * 4 + ks) * 2 + 0) * 64 + lane];
            bf16x8 al = eg[(size_t)((gct * 4 + ks) * 2 + 1) * 64 + lane];
            acc = __builtin_amdgcn_mfma_f32_32x32x16_bf16(ah, zb0[ks], acc, 0, 0, 0);
            acc = __builtin_amdgcn_mfma_f32_32x32x16_bf16(ah, zb1[ks], acc, 0, 0, 0);
            acc = __builtin_amdgcn_mfma_f32_32x32x16_bf16(al, zb0[ks], acc, 0, 0, 0);
        }
        const int jbase = gct * 32 + 4 * hi;
        #pragma unroll
        for (int r = 0; r < 16; ++r) {
            float v = acc[r];
            int j = jbase + (r & 3) + 8 * (r >> 2);
            bool b0 = v < t0, b1 = v < t1;
            t1 = b0 ? t0 : (b1 ? v : t1);
            j1 = b0 ? j0 : (b1 ? j : j1);
            t0 = b0 ? v : t0;
            j0 = b0 ? j : j0;
        }
    }

    // ---- publish candidates (indices only; rescore is exact anyway)
    __shared__ int sidx[4][64][2];
    sidx[w][lane][0] = j0;
    sidx[w][lane][1] = j1;
    __syncthreads();

    // ---- exact rescore: waves 0/2 handle their tile; 2 threads per token
    if ((w & 1) == 0) {
        const int tok = lane >> 1, hsel = lane & 1;
        const int wsrc = (w >> 1) * 2 + hsel;     // wave that scanned this half
        const int tr = (blockIdx.x * 2 + (w >> 1)) * 32 + tok;
        const float* zp = z + (size_t)(tr >> 12) * B_STRIDE + (tr & 4095);
        float zr[64];
        #pragma unroll
        for (int k = 0; k < 64; ++k) zr[k] = zp[(size_t)k * CH_STRIDE];
        // znorm: np pairwise, streamed
        float rr[8];
        #pragma unroll
        for (int m = 0; m < 8; ++m) rr[m] = __fmul_rn(zr[m], zr[m]);
        #pragma unroll
        for (int i = 8; i < 64; i += 8) {
            #pragma unroll
            for (int m = 0; m < 8; ++m)
                rr[m] = __fadd_rn(rr[m], __fmul_rn(zr[i + m], zr[i + m]));
        }
        const float zn =
            __fadd_rn(__fadd_rn(__fadd_rn(rr[0], rr[1]), __fadd_rn(rr[2], rr[3])),
                      __fadd_rn(__fadd_rn(rr[4], rr[5]), __fadd_rn(rr[6], rr[7])));

        float bd = 3.4e38f; int bj = 1 << 30;
        #pragma unroll
        for (int c = 0; c < 4; ++c) {
            const int j = sidx[wsrc][(c >> 1) * 32 + tok][c & 1];
            const float* e = emb + (size_t)j * 64;
            float a0 = 0.f;
            #pragma unroll
            for (int k = 0; k < 64; ++k) a0 = __fmaf_rn(zr[k], e[k], a0);
            float d = __fsub_rn(__fadd_rn(zn, enorm[j]), 2.0f * a0);
            if (d < bd || (d == bd && j < bj)) { bd = d; bj = j; }
        }
        // merge with partner lane (other ct-half), lex (d, j)
        float pd = __shfl_xor(bd, 1, 64);
        int pj = __shfl_xor(bj, 1, 64);
        if (pd < bd || (pd == bd && pj < bj)) { bd = pd; bj = pj; }
        if (hsel == 0) {
            ws_idx[tr] = bj;
            out_idx[tr] = (float)bj;
        }
    }
}

__global__ __launch_bounds__(256) void vq_gather(const float* __restrict__ z,
                                                 const float* __restrict__ emb,
                                                 const int* __restrict__ ws_idx,
                                                 float* __restrict__ zq,
                                                 int* __restrict__ hist,
                                                 double* __restrict__ lossAcc) {
    const int t = blockIdx.x * 256 + threadIdx.x;
    const int b = t >> 12;
    const int hw = t & 4095;
    const int idx = ws_idx[t];
    atomicAdd(&hist[idx], 1);
    const float* e = emb + (size_t)idx * ED;
    const float* zp = z + (size_t)b * B_STRIDE + hw;
    float* o = zq + (size_t)b * B_STRIDE + hw;
    double ls = 0.0;
    #pragma unroll
    for (int c = 0; c < ED; ++c) {
        float ev = e[c];
        float zv = zp[(size_t)c * CH_STRIDE];
        o[(size_t)c * CH_STRIDE] = ev;
        float d = ev - zv;
        ls += (double)(d * d);
    }
    #pragma unroll
    for (int off = 32; off > 0; off >>= 1) ls += __shfl_down(ls, off, 64);
    __shared__ double wsum[4];
    if ((threadIdx.x & 63) == 0) wsum[threadIdx.x >> 6] = ls;
    __syncthreads();
    if (threadIdx.x == 0) {
        double tot = wsum[0] + wsum[1] + wsum[2] + wsum[3];
        atomicAdd(lossAcc, tot);
    }
}

__global__ __launch_bounds__(256) void vq_final(const int* __restrict__ hist,
                                                const double* __restrict__ lossAcc,
                                                float* __restrict__ outs) {
    __shared__ double red[256];
    double acc = 0.0;
    for (int j = threadIdx.x; j < NE; j += 256) {
        double em = (double)hist[j] * (1.0 / 65536.0);
        acc += em * log(em + 1e-10);
    }
    red[threadIdx.x] = acc;
    __syncthreads();
    for (int s = 128; s > 0; s >>= 1) {
        if (threadIdx.x < s) red[threadIdx.x] += red[threadIdx.x + s];
        __syncthreads();
    }
    if (threadIdx.x == 0) {
        outs[0] = (float)(1.25 * (*lossAcc) * (1.0 / 4194304.0));
        outs[1] = (float)exp(-red[0]);
    }
}

extern "C" void kernel_launch(void* const* d_in, const int* in_sizes, int n_in,
                              void* d_out, int out_size, void* d_ws, size_t ws_size,
                              hipStream_t stream) {
    const float* z = (const float*)d_in[0];
    const float* emb = (const float*)d_in[1];
    float* out = (float*)d_out;

    char* ws = (char*)d_ws;
    ushort_t* efrag = (ushort_t*)ws;
    float* enorm = (float*)(ws + 262144);
    int* ws_idx = (int*)(ws + 266240);
    int* hist = (int*)(ws + 528384);
    double* lossAcc = (double*)(ws + 532480);

    float* zq = out;                        // [0, 4194304)
    float* scalars = out + 4194304;         // loss, perplexity
    float* out_idx = out + 4194306;         // 65536 indices as float

    vq_prep_e<<<4, 256, 0, stream>>>(emb, efrag, enorm, hist, lossAcc);
    vq_argmin_mfma<<<1024, 256, 0, stream>>>(z, efrag, enorm, emb, ws_idx, out_idx);
    vq_gather<<<256, 256, 0, stream>>>(z, emb, ws_idx, zq, hist, lossAcc);
    vq_final<<<1, 256, 0, stream>>>(hist, lossAcc, scalars);
}

// Round 6
// 49.637 us; speedup vs baseline: 3.9381x; 1.6909x over previous
//
#include <hip/hip_runtime.h>

#define TOKS 65536
#define ED 64
#define NE 1024
#define CH_STRIDE 4096      // 64*64
#define B_STRIDE 262144     // 64*64*64

typedef __bf16 bf16x8 __attribute__((ext_vector_type(8)));
typedef float f32x16 __attribute__((ext_vector_type(16)));
typedef unsigned short ushort_t;
typedef unsigned int uint_t;

// ws layout:
//   efrag @ 0      : 32ct x 4ks x 64lane x 8 bf16 (hi of -2*emb) [128 KB]
//   enorm @ 131072 : 1024 f32 (np-pairwise ||e||^2, exact)        [4 KB]
//   hist  @ 135168 : 1024 i32                                     [4 KB]
//   loss  @ 139264 : 1 f64                                        [8 B]

__device__ __forceinline__ ushort_t f2bf(float x) {
    uint_t u = __float_as_uint(x);
    uint_t r = u + 0x7FFFu + ((u >> 16) & 1u);   // RNE
    return (ushort_t)(r >> 16);
}

// ---- prep E: wave per code. enorm via shfl-replicated numpy pairwise (exact
// op order: 8 accumulators, 7 sequential stride-8 adds, 3-level tree).
__global__ __launch_bounds__(256) void vq_prep_e(const float* __restrict__ emb,
                                                 ushort_t* __restrict__ efrag,
                                                 float* __restrict__ enorm,
                                                 int* __restrict__ hist,
                                                 double* __restrict__ lossAcc) {
    const int tid = threadIdx.x;
    const int w = tid >> 6, lane = tid & 63;
    const int j = blockIdx.x * 4 + w;

    const float e = emb[j * 64 + lane];
    const float sq = __fmul_rn(e, e);
    float acc = sq;
    acc = __fadd_rn(acc, __shfl_down(sq, 8, 64));
    acc = __fadd_rn(acc, __shfl_down(sq, 16, 64));
    acc = __fadd_rn(acc, __shfl_down(sq, 24, 64));
    acc = __fadd_rn(acc, __shfl_down(sq, 32, 64));
    acc = __fadd_rn(acc, __shfl_down(sq, 40, 64));
    acc = __fadd_rn(acc, __shfl_down(sq, 48, 64));
    acc = __fadd_rn(acc, __shfl_down(sq, 56, 64));
    float x = __fadd_rn(acc, __shfl_down(acc, 1, 64));
    float y = __fadd_rn(x, __shfl_down(x, 2, 64));
    float zn = __fadd_rn(y, __shfl_down(y, 4, 64));
    if (lane == 0) enorm[j] = zn;

    const ushort_t h = f2bf(-2.0f * e);
    const int ct = j >> 5, m = j & 31;
    const int ks = lane >> 4, kh = (lane >> 3) & 1, i = lane & 7;
    efrag[(size_t)((ct * 4 + ks) * 512) + (m + 32 * kh) * 8 + i] = h;

    if (blockIdx.x < 4) hist[blockIdx.x * 256 + tid] = 0;
    if (blockIdx.x == 0 && tid == 0) *lossAcc = 0.0;
}

// ---- fused: MFMA filter + exact rescore + gather/hist/loss + zq store.
// Block = 64 tokens (2 MFMA tiles), 4 waves = 4 code-quarters (256 codes each).
// Keys: d~ = 0.25 - 2*bf16(z)hi.bf16(-2e)hi... positive -> uint-sortable,
// index packed in low 10 bits; top-3 per lane-set; exact f32 rescore decides.
__global__ __launch_bounds__(256, 4) void vq_main(
    const float* __restrict__ z,
    const ushort_t* __restrict__ efrag,
    const float* __restrict__ enorm,
    const float* __restrict__ emb,
    float* __restrict__ zq,
    float* __restrict__ out_idx,
    int* __restrict__ hist,
    double* __restrict__ lossAcc) {
    __shared__ float z_s[64][68];                 // [channel][token], padded
    __shared__ uint_t skey[4][2][32][2][3];       // [wave][tile][n][hi][slot]
    __shared__ double wsum[4];

    const int tid = threadIdx.x;
    const int w = tid >> 6, lane = tid & 63;
    const int t0 = blockIdx.x * 64;
    const int b = t0 >> 12, hw0 = t0 & 4095;
    const float* zbase = z + (size_t)b * B_STRIDE + hw0;

    // stage z tile (coalesced 256B rows per channel)
    {
        const int c = tid >> 2, u0 = (tid & 3) * 16;
        const float4* src = (const float4*)(zbase + (size_t)c * CH_STRIDE + u0);
        float4 f0 = src[0], f1 = src[1], f2 = src[2], f3 = src[3];
        float4* dst = (float4*)&z_s[c][u0];
        dst[0] = f0; dst[1] = f1; dst[2] = f2; dst[3] = f3;
    }
    __syncthreads();

    const int n = lane & 31, kh = lane >> 5;

    // B-frags: bf16(z) hi-plane only, tiles A (tok 0-31) and B (tok 32-63)
    bf16x8 zbA[4], zbB[4];
    #pragma unroll
    for (int ks = 0; ks < 4; ++ks) {
        #pragma unroll
        for (int i = 0; i < 8; ++i) {
            const int k = ks * 16 + kh * 8 + i;
            union { ushort_t u; __bf16 bh; } ca, cb;
            ca.u = f2bf(z_s[k][n]);
            cb.u = f2bf(z_s[k][32 + n]);
            zbA[ks][i] = ca.bh;
            zbB[ks][i] = cb.bh;
        }
    }

    uint_t kA0 = 0xFFFFFFFFu, kA1 = 0xFFFFFFFFu, kA2 = 0xFFFFFFFFu;
    uint_t kB0 = 0xFFFFFFFFu, kB1 = 0xFFFFFFFFu, kB2 = 0xFFFFFFFFu;
    const bf16x8* eg = (const bf16x8*)efrag;

    #pragma unroll
    for (int ct = 0; ct < 8; ++ct) {
        const int gct = w * 8 + ct;
        bf16x8 ah[4];
        #pragma unroll
        for (int ks = 0; ks < 4; ++ks)
            ah[ks] = eg[(size_t)(gct * 4 + ks) * 64 + lane];

        const int jb = gct * 32 + 4 * kh;

        f32x16 acc;
        #pragma unroll
        for (int r = 0; r < 16; ++r) acc[r] = 0.25f;
        #pragma unroll
        for (int ks = 0; ks < 4; ++ks)
            acc = __builtin_amdgcn_mfma_f32_32x32x16_bf16(ah[ks], zbA[ks], acc, 0, 0, 0);
        #pragma unroll
        for (int r = 0; r < 16; ++r) {
            uint_t key = (__float_as_uint(acc[r]) & 0xFFFFFC00u)
                         | (uint_t)(jb + (r & 3) + 8 * (r >> 2));
            uint_t mx = max(kA0, key);
            kA2 = min(kA2, max(kA1, mx));
            kA1 = min(kA1, mx);
            kA0 = min(kA0, key);
        }

        #pragma unroll
        for (int r = 0; r < 16; ++r) acc[r] = 0.25f;
        #pragma unroll
        for (int ks = 0; ks < 4; ++ks)
            acc = __builtin_amdgcn_mfma_f32_32x32x16_bf16(ah[ks], zbB[ks], acc, 0, 0, 0);
        #pragma unroll
        for (int r = 0; r < 16; ++r) {
            uint_t key = (__float_as_uint(acc[r]) & 0xFFFFFC00u)
                         | (uint_t)(jb + (r & 3) + 8 * (r >> 2));
            uint_t mx = max(kB0, key);
            kB2 = min(kB2, max(kB1, mx));
            kB1 = min(kB1, mx);
            kB0 = min(kB0, key);
        }
    }

    skey[w][0][n][kh][0] = kA0; skey[w][0][n][kh][1] = kA1; skey[w][0][n][kh][2] = kA2;
    skey[w][1][n][kh][0] = kB0; skey[w][1][n][kh][1] = kB1; skey[w][1][n][kh][2] = kB2;
    __syncthreads();

    // ---- exact rescore: 4 threads per token, 6 candidates each
    const int t_loc = tid >> 2, cw = tid & 3;
    const int tile = t_loc >> 5, nn = t_loc & 31;
    uint_t ck[6];
    #pragma unroll
    for (int hi = 0; hi < 2; ++hi)
        #pragma unroll
        for (int s = 0; s < 3; ++s)
            ck[hi * 3 + s] = skey[cw][tile][nn][hi][s];

    uint_t kmin = ck[0];
    #pragma unroll
    for (int c2 = 1; c2 < 6; ++c2) kmin = min(kmin, ck[c2]);
    kmin = min(kmin, (uint_t)__shfl_xor((int)kmin, 1, 64));
    kmin = min(kmin, (uint_t)__shfl_xor((int)kmin, 2, 64));
    const float thr = __uint_as_float(kmin & 0xFFFFFC00u) + 4.0e-4f;

    // znorm: numpy pairwise, exact op order, streamed from LDS
    float rr[8];
    #pragma unroll
    for (int m = 0; m < 8; ++m) {
        float a = z_s[m][t_loc];
        rr[m] = __fmul_rn(a, a);
    }
    #pragma unroll
    for (int i = 8; i < 64; i += 8) {
        #pragma unroll
        for (int m = 0; m < 8; ++m) {
            float a = z_s[i + m][t_loc];
            rr[m] = __fadd_rn(rr[m], __fmul_rn(a, a));
        }
    }
    const float zn =
        __fadd_rn(__fadd_rn(__fadd_rn(rr[0], rr[1]), __fadd_rn(rr[2], rr[3])),
                  __fadd_rn(__fadd_rn(rr[4], rr[5]), __fadd_rn(rr[6], rr[7])));

    float bd = 3.4e38f; int bj = 1 << 30;
    #pragma unroll
    for (int c2 = 0; c2 < 6; ++c2) {
        const float vc = __uint_as_float(ck[c2] & 0xFFFFFC00u);
        if (vc <= thr) {
            const int j = (int)(ck[c2] & 1023u);
            const float* e = emb + (size_t)j * 64;
            float a0 = 0.f;
            #pragma unroll
            for (int k4 = 0; k4 < 64; k4 += 4) {
                float4 e4 = *(const float4*)(e + k4);
                a0 = __fmaf_rn(z_s[k4 + 0][t_loc], e4.x, a0);
                a0 = __fmaf_rn(z_s[k4 + 1][t_loc], e4.y, a0);
                a0 = __fmaf_rn(z_s[k4 + 2][t_loc], e4.z, a0);
                a0 = __fmaf_rn(z_s[k4 + 3][t_loc], e4.w, a0);
            }
            float d = __fsub_rn(__fadd_rn(zn, enorm[j]), 2.0f * a0);
            if (d < bd || (d == bd && j < bj)) { bd = d; bj = j; }
        }
    }
    // quad lex-(d,j) merge -> np first-occurrence argmin
    {
        float pd = __shfl_xor(bd, 1, 64); int pj = __shfl_xor(bj, 1, 64);
        if (pd < bd || (pd == bd && pj < bj)) { bd = pd; bj = pj; }
        pd = __shfl_xor(bd, 2, 64); pj = __shfl_xor(bj, 2, 64);
        if (pd < bd || (pd == bd && pj < bj)) { bd = pd; bj = pj; }
    }

    double ls = 0.0;
    if (cw == 0) {
        out_idx[t0 + t_loc] = (float)bj;
        atomicAdd(&hist[bj], 1);
        const float* e = emb + (size_t)bj * 64;
        #pragma unroll
        for (int k = 0; k < 64; ++k) {
            float ev = e[k];
            float zv = z_s[k][t_loc];
            z_s[k][t_loc] = ev;                    // tile becomes z_q
            float df = ev - zv;
            ls += (double)(df * df);
        }
    }
    #pragma unroll
    for (int off = 32; off > 0; off >>= 1) ls += __shfl_down(ls, off, 64);
    if (lane == 0) wsum[w] = ls;
    __syncthreads();                               // z_s fully z_q; wsum ready
    if (tid == 0)
        atomicAdd(lossAcc, wsum[0] + wsum[1] + wsum[2] + wsum[3]);

    // coalesced z_q store
    {
        const int c = tid >> 2, u0 = (tid & 3) * 16;
        const float4* s4 = (const float4*)&z_s[c][u0];
        float4 f0 = s4[0], f1 = s4[1], f2 = s4[2], f3 = s4[3];
        float4* dst = (float4*)(zq + (size_t)b * B_STRIDE + (size_t)c * CH_STRIDE + hw0 + u0);
        dst[0] = f0; dst[1] = f1; dst[2] = f2; dst[3] = f3;
    }
}

__global__ __launch_bounds__(256) void vq_final(const int* __restrict__ hist,
                                                const double* __restrict__ lossAcc,
                                                float* __restrict__ outs) {
    __shared__ double red[256];
    double acc = 0.0;
    for (int j = threadIdx.x; j < NE; j += 256) {
        double em = (double)hist[j] * (1.0 / 65536.0);
        acc += em * log(em + 1e-10);
    }
    red[threadIdx.x] = acc;
    __syncthreads();
    for (int s = 128; s > 0; s >>= 1) {
        if (threadIdx.x < s) red[threadIdx.x] += red[threadIdx.x + s];
        __syncthreads();
    }
    if (threadIdx.x == 0) {
        outs[0] = (float)(1.25 * (*lossAcc) * (1.0 / 4194304.0));
        outs[1] = (float)exp(-red[0]);
    }
}

extern "C" void kernel_launch(void* const* d_in, const int* in_sizes, int n_in,
                              void* d_out, int out_size, void* d_ws, size_t ws_size,
                              hipStream_t stream) {
    const float* z = (const float*)d_in[0];
    const float* emb = (const float*)d_in[1];
    float* out = (float*)d_out;

    char* ws = (char*)d_ws;
    ushort_t* efrag = (ushort_t*)ws;
    float* enorm = (float*)(ws + 131072);
    int* hist = (int*)(ws + 135168);
    double* lossAcc = (double*)(ws + 139264);

    float* zq = out;                        // [0, 4194304)
    float* scalars = out + 4194304;         // loss, perplexity
    float* out_idx = out + 4194306;         // 65536 indices as float

    vq_prep_e<<<256, 256, 0, stream>>>(emb, efrag, enorm, hist, lossAcc);
    vq_main<<<1024, 256, 0, stream>>>(z, efrag, enorm, emb, zq, out_idx, hist, lossAcc);
    vq_final<<<1, 256, 0, stream>>>(hist, lossAcc, scalars);
}